// Round 15
// baseline (64.827 us; speedup 1.0000x reference)
//
#include <hip/hip_runtime.h>
#include <hip/hip_bf16.h>

// Multi-resolution dense 3x3x3 conv, CIN=COUT=16, bf16 MFMA, 3D LDS tiling.
// R14: R13 (operand-swap + full-line nt stores, 62.3us) + WEIGHT REGISTER
// PRELOAD: all 15 bf16x8 weight fragments loaded once per block (issued after
// the staging ds_writes, L2 latency hides under the barrier wait) instead of
// 3 global loads inside every duo iteration — removes 5x ~250cyc L2 latency
// from the compute critical path. raw[12] is dead before W[15] goes live, so
// peak VGPR ~110 fits the (256,4) 128-cap without spill.
// Structure: tile 4x4x16, 9426 blocks, branch-free clamped batched staging,
// 5 (dx,dz)-duos x 3 dy, one ds_read_b128 feeds 3 MFMAs, D[co][z] output.

typedef short bf16x8 __attribute__((ext_vector_type(8)));
typedef float f32x4  __attribute__((ext_vector_type(4)));

__device__ __forceinline__ unsigned f2bf(float f) {
    unsigned u = __float_as_uint(f);
    return (u + 0x7FFFu + ((u >> 16) & 1u)) >> 16;   // RNE
}
__device__ __forceinline__ unsigned pk2(float lo, float hi) {
    __hip_bfloat162 t = __float22bfloat162_rn(float2{lo, hi});
    return *reinterpret_cast<unsigned*>(&t);
}

__device__ __constant__ int c_DX0[5] = {-1,-1, 0, 1, 1};
__device__ __constant__ int c_DZ0[5] = {-1, 1, 0,-1, 1};
__device__ __constant__ int c_DX1[5] = {-1, 0, 0, 1, 1};
__device__ __constant__ int c_DZ1[5] = { 0,-1, 1, 0, 1};

// ---------------- pass 1: weight fragments in duo order ----------------
// wf2[lvl][duo][dyi][lane]: 8 bf16, elem j -> w[lvl][s][ci][co],
// s from (dx,dz) duo member (lane>>5) and dy=dyi; ci = ((lane>>4)&1)*8 + j,
// co = lane&15. Serves as MFMA A operand: A[m=co][k], k-block = lane>>4,
// identical k-mapping to the G fragment. duo4/ksel1 -> 0.
__global__ __launch_bounds__(64) void wfrag2_kernel(const float* __restrict__ wgt,
                                                    uint4* __restrict__ wf2) {
    const int b = blockIdx.x;                  // lvl*15 + duo*3 + dyi
    const int lvl = b / 15, rem = b % 15, duo = rem / 3, dyi = rem % 3;
    const int l = threadIdx.x;
    const int ksel = l >> 5;
    const int cib = ((l >> 4) & 1) * 8;
    const int co = l & 15;
    const bool zerow = (duo == 4) && (ksel == 1);
    const int dx = ksel ? c_DX1[duo] : c_DX0[duo];
    const int dz = ksel ? c_DZ1[duo] : c_DZ0[duo];
    const int s = (dx + 1) * 9 + dyi * 3 + (dz + 1);
    unsigned v[8];
#pragma unroll
    for (int j = 0; j < 8; ++j) {
        float f = zerow ? 0.f : wgt[(((lvl * 27 + s) * 16) + (cib + j)) * 16 + co];
        v[j] = f2bf(f);
    }
    uint4 pk;
    pk.x = v[0] | (v[1] << 16);
    pk.y = v[2] | (v[3] << 16);
    pk.z = v[4] | (v[5] << 16);
    pk.w = v[6] | (v[7] << 16);
    wf2[((lvl * 5 + duo) * 3 + dyi) * 64 + l] = pk;
}

// ---------------- pass 2: tiled MFMA conv ----------------
#define CTPB 256
#define NTILEBLKS 9426
#define PLANE 10432          // 648 halo voxels * 16B + 64B bank-phase pad

__global__ __launch_bounds__(CTPB, 4) void conv_mfma_tile_kernel(
    const float* __restrict__ in, const ushort* __restrict__ wf2,
    const float* __restrict__ bias, float* __restrict__ out)
{
    constexpr int RES[16]   = {16, 18, 20, 23, 26, 29, 32, 36, 40, 45, 50, 56, 63, 70, 76, 80};
    constexpr int OFF[16]   = {0, 4096, 9928, 17928, 30095, 47671, 72060, 104828,
                               151484, 215484, 306609, 431609, 607225, 857272, 1200272, 1639248};
    // tiles per level = ceil(r/4)^2 * ceil(r/16); prefix:
    constexpr int TBOFF[16] = {0, 16, 66, 116, 188, 286, 414, 542, 785, 1085,
                               1517, 2193, 2977, 4001, 5621, 7426};
    // per-duo LDS byte shifts: (dx*108 + dz)*16 for members 0/1
    constexpr int SH0[5] = {-1744, -1712, 0, 1712, 1744};
    constexpr int SH1[5] = {-1728, -16, 16, 1728, 1744};

    __shared__ __align__(16) char lds[2 * PLANE];   // 20.9 KB

    // Bijective XCD swizzle (nwg=9426, q=1178, r=2): neighbors share an XCD L2.
    const int orig = blockIdx.x;
    const int xcd = orig & 7, idx = orig >> 3;
    const int b = (xcd < 2 ? xcd * 1179 : 2 * 1179 + (xcd - 2) * 1178) + idx;

    int lvl = 0;
#pragma unroll
    for (int i = 1; i < 16; ++i) if (b >= TBOFF[i]) lvl = i;
    const int r    = RES[lvl];
    const int base = OFF[lvl];

    const int NTZ = (r + 15) >> 4;
    const int NTY = (r + 3) >> 2;
    int tid = b - TBOFF[lvl];
    const int nyz = NTY * NTZ;
    const int txi = tid / nyz;  tid -= txi * nyz;
    const int tyi = tid / NTZ;
    const int tzi = tid - tyi * NTZ;
    const int x0 = txi * 4, y0 = tyi * 4, z0 = tzi * 16;

    const int lane = threadIdx.x & 63;
    const int wave = threadIdx.x >> 6;

    // ---- stage, phase A: 12 unconditional clamped loads (branch-free) ----
    float4 raw[12];
    int    lofs[6];
    bool   val[6];
#pragma unroll
    for (int k = 0; k < 6; ++k) {
        const int j = (int)threadIdx.x + k * 256;
        const int half = j & 1;
        int h = j >> 1;
        if (k == 5) h = h > 647 ? 647 : h;       // overrun threads: clamp slot
        const int hx = h / 108;
        const int rem = h - hx * 108;
        const int hy = rem / 18;
        const int hz = rem - hy * 18;
        const int gx = x0 - 1 + hx, gy = y0 - 1 + hy, gz = z0 - 1 + hz;
        const bool v = ((unsigned)gx < (unsigned)r) & ((unsigned)gy < (unsigned)r) &
                       ((unsigned)gz < (unsigned)r);
        const int cx = gx < 0 ? 0 : (gx >= r ? r - 1 : gx);
        const int cy = gy < 0 ? 0 : (gy >= r ? r - 1 : gy);
        const int cz = gz < 0 ? 0 : (gz >= r ? r - 1 : gz);
        const float4* s = reinterpret_cast<const float4*>(
            in + ((size_t)base + ((size_t)cx * r + cy) * r + cz) * 16 + half * 8);
        raw[2 * k]     = s[0];
        raw[2 * k + 1] = s[1];
        val[k]  = v;
        lofs[k] = half * PLANE + h * 16;
    }
    __builtin_amdgcn_sched_barrier(0);   // keep loads batched above this point

    // ---- stage, phase B: cvt (unconditional) + mask + ds_write ----
#pragma unroll
    for (int k = 0; k < 6; ++k) {
        const float4 a = raw[2 * k], c2 = raw[2 * k + 1];
        uint4 pkv;
        pkv.x = pk2(a.x,  a.y);
        pkv.y = pk2(a.z,  a.w);
        pkv.z = pk2(c2.x, c2.y);
        pkv.w = pk2(c2.z, c2.w);
        if (!val[k]) pkv = uint4{0u, 0u, 0u, 0u};
        if (k < 5 || threadIdx.x < 16)
            *reinterpret_cast<uint4*>(lds + lofs[k]) = pkv;
    }

    // ---- weight register preload: all 15 fragments (L2 latency hides under
    // the barrier wait; raw[] is dead so peak VGPR stays under the 128 cap) ----
    bf16x8 W[15];
    {
        const bf16x8* wl = (const bf16x8*)wf2 + (size_t)lvl * 15 * 64 + lane;
#pragma unroll
        for (int t = 0; t < 15; ++t) W[t] = wl[t * 64];
    }
    __syncthreads();

    // ---- compute: wave = x-slice tx, 4 y-cols, 5 duos x (6 reads + 12 MFMA) ----
    const int m      = lane & 15;         // z within tile (B-operand N index)
    const int cihalf = (lane >> 4) & 1;
    const int ksel   = lane >> 5;
    const int tx     = wave;

    // lane base at duo-shift 0, halo row y'=0: voxel (tx+1, 0, 1+m)
    const int base0 = cihalf * PLANE + ((tx + 1) * 108 + 1 + m) * 16;

    f32x4 acc[4];
#pragma unroll
    for (int i = 0; i < 4; ++i) acc[i] = f32x4{0.f, 0.f, 0.f, 0.f};

#pragma unroll
    for (int d = 0; d < 5; ++d) {
        const int shift = ksel ? SH1[d] : SH0[d];
        const char* gp = lds + (base0 + shift);

        bf16x8 G[6];
#pragma unroll
        for (int y = 0; y < 6; ++y)
            G[y] = *reinterpret_cast<const bf16x8*>(gp + y * 288);

        // OPERAND SWAP: A = weights (M=co), B = G (N=z) -> D[co][z]
        __builtin_amdgcn_s_setprio(1);
#pragma unroll
        for (int i = 0; i < 4; ++i)
            acc[i] = __builtin_amdgcn_mfma_f32_16x16x32_bf16(W[3*d],     G[i],     acc[i], 0, 0, 0);
#pragma unroll
        for (int i = 0; i < 4; ++i)
            acc[i] = __builtin_amdgcn_mfma_f32_16x16x32_bf16(W[3*d + 1], G[i + 1], acc[i], 0, 0, 0);
#pragma unroll
        for (int i = 0; i < 4; ++i)
            acc[i] = __builtin_amdgcn_mfma_f32_16x16x32_bf16(W[3*d + 2], G[i + 2], acc[i], 0, 0, 0);
        __builtin_amdgcn_s_setprio(0);
    }

    // ---- store (+bias), NONTEMPORAL dwordx4: lane = (z = lane&15,
    // channels 4*(lane>>4)..+3). Wave store = contiguous 1KB (full lines). ----
    const int cob = (lane >> 4) * 4;
    const f32x4 bv4 = *reinterpret_cast<const f32x4*>(&bias[lvl * 16 + cob]);
    const int gx = x0 + tx;
    const int zr = z0 + m;
    if ((gx < r) & (zr < r)) {
#pragma unroll
        for (int i = 0; i < 4; ++i) {
            const int gy = y0 + i;
            if (gy >= r) continue;
            float* p = out + ((size_t)base + ((size_t)gx * r + gy) * r + zr) * 16 + cob;
            const f32x4 v = acc[i] + bv4;
            __builtin_nontemporal_store(v, reinterpret_cast<f32x4*>(p));
        }
    }
}

// ---------------- fp32 fallback (round-0 verified, used only if ws tiny) -----
#define TPB 256
#define VPT 2
#define VPB (TPB * VPT)
#define NBLOCKS_F32 4207

__global__ __launch_bounds__(TPB) void conv3d_mr_kernel(
    const float* __restrict__ in, const float* __restrict__ wgt,
    const float* __restrict__ bias, float* __restrict__ out)
{
    constexpr int RES[16]  = {16, 18, 20, 23, 26, 29, 32, 36, 40, 45, 50, 56, 63, 70, 76, 80};
    constexpr int OFF[16]  = {0, 4096, 9928, 17928, 30095, 47671, 72060, 104828,
                              151484, 215484, 306609, 431609, 607225, 857272, 1200272, 1639248};
    constexpr int BOFF[16] = {0, 8, 20, 36, 60, 95, 143, 207, 299, 424, 602, 847, 1190, 1679, 2349, 3207};

    __shared__ __align__(16) float w_lds[27 * 256];

    const int b = blockIdx.x;
    int r = RES[0], base = OFF[0], bstart = BOFF[0], lvl = 0;
#pragma unroll
    for (int i = 1; i < 16; ++i)
        if (b >= BOFF[i]) { lvl = i; r = RES[i]; base = OFF[i]; bstart = BOFF[i]; }
    const int t3 = r * r * r;
    const int vstart = (b - bstart) * VPB;

    {
        const float4* ws = reinterpret_cast<const float4*>(wgt + lvl * 27 * 256);
        float4* wd = reinterpret_cast<float4*>(w_lds);
        for (int i = threadIdx.x; i < 27 * 64; i += TPB) wd[i] = ws[i];
    }
    __syncthreads();

    float bv[16];
    {
        const float4* bp = reinterpret_cast<const float4*>(bias + lvl * 16);
#pragma unroll
        for (int j = 0; j < 4; ++j) {
            float4 t = bp[j];
            bv[4*j+0] = t.x; bv[4*j+1] = t.y; bv[4*j+2] = t.z; bv[4*j+3] = t.w;
        }
    }

    int vx[VPT], vy[VPT], vz[VPT];
    bool live[VPT];
    float acc[VPT][16];
#pragma unroll
    for (int i = 0; i < VPT; ++i) {
        int v = vstart + (int)threadIdx.x + i * TPB;
        live[i] = (v < t3);
        if (!live[i]) v = 0;
        const int q = v / r;
        vz[i] = v - q * r; vx[i] = q / r; vy[i] = q - vx[i] * r;
#pragma unroll
        for (int co = 0; co < 16; ++co) acc[i][co] = bv[co];
    }

#pragma unroll 1
    for (int k = 0; k < 27; ++k) {
        const int dx = k / 9 - 1, dy = (k / 3) % 3 - 1, dz = k - (k / 3) * 3 - 1;
        float g[VPT][16];
#pragma unroll
        for (int i = 0; i < VPT; ++i) {
            const int nx = vx[i] + dx, ny = vy[i] + dy, nz = vz[i] + dz;
            const bool ok = live[i] && ((unsigned)nx < (unsigned)r) &&
                            ((unsigned)ny < (unsigned)r) && ((unsigned)nz < (unsigned)r);
            float4 a0 = make_float4(0.f,0.f,0.f,0.f), a1 = a0, a2 = a0, a3 = a0;
            if (ok) {
                const float4* p = reinterpret_cast<const float4*>(
                    in + (size_t)(base + (nx * r + ny) * r + nz) * 16);
                a0 = p[0]; a1 = p[1]; a2 = p[2]; a3 = p[3];
            }
            g[i][0]=a0.x; g[i][1]=a0.y; g[i][2]=a0.z; g[i][3]=a0.w;
            g[i][4]=a1.x; g[i][5]=a1.y; g[i][6]=a1.z; g[i][7]=a1.w;
            g[i][8]=a2.x; g[i][9]=a2.y; g[i][10]=a2.z; g[i][11]=a2.w;
            g[i][12]=a3.x; g[i][13]=a3.y; g[i][14]=a3.z; g[i][15]=a3.w;
        }
        const float4* wk = reinterpret_cast<const float4*>(&w_lds[k * 256]);
#pragma unroll
        for (int ci = 0; ci < 16; ++ci) {
            const float4 w0 = wk[ci*4+0], w1 = wk[ci*4+1], w2 = wk[ci*4+2], w3 = wk[ci*4+3];
#pragma unroll
            for (int i = 0; i < VPT; ++i) {
                const float gv = g[i][ci];
                acc[i][0]=fmaf(gv,w0.x,acc[i][0]);   acc[i][1]=fmaf(gv,w0.y,acc[i][1]);
                acc[i][2]=fmaf(gv,w0.z,acc[i][2]);   acc[i][3]=fmaf(gv,w0.w,acc[i][3]);
                acc[i][4]=fmaf(gv,w1.x,acc[i][4]);   acc[i][5]=fmaf(gv,w1.y,acc[i][5]);
                acc[i][6]=fmaf(gv,w1.z,acc[i][6]);   acc[i][7]=fmaf(gv,w1.w,acc[i][7]);
                acc[i][8]=fmaf(gv,w2.x,acc[i][8]);   acc[i][9]=fmaf(gv,w2.y,acc[i][9]);
                acc[i][10]=fmaf(gv,w2.z,acc[i][10]); acc[i][11]=fmaf(gv,w2.w,acc[i][11]);
                acc[i][12]=fmaf(gv,w3.x,acc[i][12]); acc[i][13]=fmaf(gv,w3.y,acc[i][13]);
                acc[i][14]=fmaf(gv,w3.z,acc[i][14]); acc[i][15]=fmaf(gv,w3.w,acc[i][15]);
            }
        }
    }

#pragma unroll
    for (int i = 0; i < VPT; ++i) {
        if (!live[i]) continue;
        const int v = vstart + (int)threadIdx.x + i * TPB;
        float4* po = reinterpret_cast<float4*>(out + (size_t)(base + v) * 16);
        po[0] = make_float4(acc[i][0],  acc[i][1],  acc[i][2],  acc[i][3]);
        po[1] = make_float4(acc[i][4],  acc[i][5],  acc[i][6],  acc[i][7]);
        po[2] = make_float4(acc[i][8],  acc[i][9],  acc[i][10], acc[i][11]);
        po[3] = make_float4(acc[i][12], acc[i][13], acc[i][14], acc[i][15]);
    }
}

extern "C" void kernel_launch(void* const* d_in, const int* in_sizes, int n_in,
                              void* d_out, int out_size, void* d_ws, size_t ws_size,
                              hipStream_t stream) {
    const float* in   = (const float*)d_in[0];
    const float* wgt  = (const float*)d_in[3];
    const float* bias = (const float*)d_in[4];
    float* out = (float*)d_out;

    constexpr size_t WF2_BYTES = 16 * 5 * 3 * 64 * 16;   // 245,760
    if (ws_size < WF2_BYTES) {
        conv3d_mr_kernel<<<NBLOCKS_F32, TPB, 0, stream>>>(in, wgt, bias, out);
        return;
    }

    uint4* wf2 = (uint4*)d_ws;
    wfrag2_kernel<<<16 * 5 * 3, 64, 0, stream>>>(wgt, wf2);
    conv_mfma_tile_kernel<<<NTILEBLKS, CTPB, 0, stream>>>(
        in, (const ushort*)wf2, bias, out);
}

// Round 16
// 62.776 us; speedup vs baseline: 1.0327x; 1.0327x over previous
//
#include <hip/hip_runtime.h>
#include <hip/hip_bf16.h>

// Multi-resolution dense 3x3x3 conv, CIN=COUT=16, bf16 MFMA, 3D LDS tiling.
// R15: R13 revert (operand-swap + full-line nt stores, 62.3us proven; R14's
// W-preload regressed and is removed) + sched_group_barrier LOAD CLUSTERING:
// pin the staging region's emission order to {addr math (VALU/SALU)} then
// {12 contiguous VMEM reads} — with no uses between the loads, the compiler
// cannot recycle dest registers, so all 12 global_load_dwordx4 stay in
// flight (one memory latency per block instead of ~6). Zero runtime cost.
// Structure: tile 4x4x16, 9426 blocks, branch-free clamped batched staging,
// 5 (dx,dz)-duos x 3 dy, one ds_read_b128 feeds 3 MFMAs, D[co][z] output.

typedef short bf16x8 __attribute__((ext_vector_type(8)));
typedef float f32x4  __attribute__((ext_vector_type(4)));

__device__ __forceinline__ unsigned f2bf(float f) {
    unsigned u = __float_as_uint(f);
    return (u + 0x7FFFu + ((u >> 16) & 1u)) >> 16;   // RNE
}
__device__ __forceinline__ unsigned pk2(float lo, float hi) {
    __hip_bfloat162 t = __float22bfloat162_rn(float2{lo, hi});
    return *reinterpret_cast<unsigned*>(&t);
}

__device__ __constant__ int c_DX0[5] = {-1,-1, 0, 1, 1};
__device__ __constant__ int c_DZ0[5] = {-1, 1, 0,-1, 1};
__device__ __constant__ int c_DX1[5] = {-1, 0, 0, 1, 1};
__device__ __constant__ int c_DZ1[5] = { 0,-1, 1, 0, 1};

// ---------------- pass 1: weight fragments in duo order ----------------
// wf2[lvl][duo][dyi][lane]: 8 bf16, elem j -> w[lvl][s][ci][co],
// s from (dx,dz) duo member (lane>>5) and dy=dyi; ci = ((lane>>4)&1)*8 + j,
// co = lane&15. Serves as MFMA A operand: A[m=co][k], k-block = lane>>4,
// identical k-mapping to the G fragment. duo4/ksel1 -> 0.
__global__ __launch_bounds__(64) void wfrag2_kernel(const float* __restrict__ wgt,
                                                    uint4* __restrict__ wf2) {
    const int b = blockIdx.x;                  // lvl*15 + duo*3 + dyi
    const int lvl = b / 15, rem = b % 15, duo = rem / 3, dyi = rem % 3;
    const int l = threadIdx.x;
    const int ksel = l >> 5;
    const int cib = ((l >> 4) & 1) * 8;
    const int co = l & 15;
    const bool zerow = (duo == 4) && (ksel == 1);
    const int dx = ksel ? c_DX1[duo] : c_DX0[duo];
    const int dz = ksel ? c_DZ1[duo] : c_DZ0[duo];
    const int s = (dx + 1) * 9 + dyi * 3 + (dz + 1);
    unsigned v[8];
#pragma unroll
    for (int j = 0; j < 8; ++j) {
        float f = zerow ? 0.f : wgt[(((lvl * 27 + s) * 16) + (cib + j)) * 16 + co];
        v[j] = f2bf(f);
    }
    uint4 pk;
    pk.x = v[0] | (v[1] << 16);
    pk.y = v[2] | (v[3] << 16);
    pk.z = v[4] | (v[5] << 16);
    pk.w = v[6] | (v[7] << 16);
    wf2[((lvl * 5 + duo) * 3 + dyi) * 64 + l] = pk;
}

// ---------------- pass 2: tiled MFMA conv ----------------
#define CTPB 256
#define NTILEBLKS 9426
#define PLANE 10432          // 648 halo voxels * 16B + 64B bank-phase pad

__global__ __launch_bounds__(CTPB, 4) void conv_mfma_tile_kernel(
    const float* __restrict__ in, const ushort* __restrict__ wf2,
    const float* __restrict__ bias, float* __restrict__ out)
{
    constexpr int RES[16]   = {16, 18, 20, 23, 26, 29, 32, 36, 40, 45, 50, 56, 63, 70, 76, 80};
    constexpr int OFF[16]   = {0, 4096, 9928, 17928, 30095, 47671, 72060, 104828,
                               151484, 215484, 306609, 431609, 607225, 857272, 1200272, 1639248};
    // tiles per level = ceil(r/4)^2 * ceil(r/16); prefix:
    constexpr int TBOFF[16] = {0, 16, 66, 116, 188, 286, 414, 542, 785, 1085,
                               1517, 2193, 2977, 4001, 5621, 7426};
    // per-duo LDS byte shifts: (dx*108 + dz)*16 for members 0/1
    constexpr int SH0[5] = {-1744, -1712, 0, 1712, 1744};
    constexpr int SH1[5] = {-1728, -16, 16, 1728, 1744};

    __shared__ __align__(16) char lds[2 * PLANE];   // 20.9 KB

    // Bijective XCD swizzle (nwg=9426, q=1178, r=2): neighbors share an XCD L2.
    const int orig = blockIdx.x;
    const int xcd = orig & 7, idx = orig >> 3;
    const int b = (xcd < 2 ? xcd * 1179 : 2 * 1179 + (xcd - 2) * 1178) + idx;

    int lvl = 0;
#pragma unroll
    for (int i = 1; i < 16; ++i) if (b >= TBOFF[i]) lvl = i;
    const int r    = RES[lvl];
    const int base = OFF[lvl];

    const int NTZ = (r + 15) >> 4;
    const int NTY = (r + 3) >> 2;
    int tid = b - TBOFF[lvl];
    const int nyz = NTY * NTZ;
    const int txi = tid / nyz;  tid -= txi * nyz;
    const int tyi = tid / NTZ;
    const int tzi = tid - tyi * NTZ;
    const int x0 = txi * 4, y0 = tyi * 4, z0 = tzi * 16;

    const int lane = threadIdx.x & 63;
    const int wave = threadIdx.x >> 6;

    // ---- stage, phase A: 12 unconditional clamped loads (branch-free) ----
    float4 raw[12];
    int    lofs[6];
    bool   val[6];
#pragma unroll
    for (int k = 0; k < 6; ++k) {
        const int j = (int)threadIdx.x + k * 256;
        const int half = j & 1;
        int h = j >> 1;
        if (k == 5) h = h > 647 ? 647 : h;       // overrun threads: clamp slot
        const int hx = h / 108;
        const int rem = h - hx * 108;
        const int hy = rem / 18;
        const int hz = rem - hy * 18;
        const int gx = x0 - 1 + hx, gy = y0 - 1 + hy, gz = z0 - 1 + hz;
        const bool v = ((unsigned)gx < (unsigned)r) & ((unsigned)gy < (unsigned)r) &
                       ((unsigned)gz < (unsigned)r);
        const int cx = gx < 0 ? 0 : (gx >= r ? r - 1 : gx);
        const int cy = gy < 0 ? 0 : (gy >= r ? r - 1 : gy);
        const int cz = gz < 0 ? 0 : (gz >= r ? r - 1 : gz);
        const float4* s = reinterpret_cast<const float4*>(
            in + ((size_t)base + ((size_t)cx * r + cy) * r + cz) * 16 + half * 8);
        raw[2 * k]     = s[0];
        raw[2 * k + 1] = s[1];
        val[k]  = v;
        lofs[k] = half * PLANE + h * 16;
    }
    // Pin emission order of this scheduling region: address math (VALU/SALU)
    // first, then ALL 12 VMEM reads back-to-back. With no uses between the
    // loads, dest registers can't be recycled -> all 12 loads stay in flight.
    __builtin_amdgcn_sched_group_barrier(0x0006, 200, 0);  // VALU|SALU chunk
    __builtin_amdgcn_sched_group_barrier(0x0020, 12, 0);   // 12 VMEM reads
    __builtin_amdgcn_sched_barrier(0);   // close region; uses stay below

    // ---- stage, phase B: cvt (unconditional) + mask + ds_write ----
#pragma unroll
    for (int k = 0; k < 6; ++k) {
        const float4 a = raw[2 * k], c2 = raw[2 * k + 1];
        uint4 pkv;
        pkv.x = pk2(a.x,  a.y);
        pkv.y = pk2(a.z,  a.w);
        pkv.z = pk2(c2.x, c2.y);
        pkv.w = pk2(c2.z, c2.w);
        if (!val[k]) pkv = uint4{0u, 0u, 0u, 0u};
        if (k < 5 || threadIdx.x < 16)
            *reinterpret_cast<uint4*>(lds + lofs[k]) = pkv;
    }
    __syncthreads();

    // ---- compute: wave = x-slice tx, 4 y-cols, 5 duos x (6 reads + 12 MFMA) ----
    const int m      = lane & 15;         // z within tile (B-operand N index)
    const int cihalf = (lane >> 4) & 1;
    const int ksel   = lane >> 5;
    const int tx     = wave;

    // lane base at duo-shift 0, halo row y'=0: voxel (tx+1, 0, 1+m)
    const int base0 = cihalf * PLANE + ((tx + 1) * 108 + 1 + m) * 16;

    f32x4 acc[4];
#pragma unroll
    for (int i = 0; i < 4; ++i) acc[i] = f32x4{0.f, 0.f, 0.f, 0.f};

#pragma unroll
    for (int d = 0; d < 5; ++d) {
        const int shift = ksel ? SH1[d] : SH0[d];
        const char* gp = lds + (base0 + shift);

        const bf16x8* wl = (const bf16x8*)wf2 + ((size_t)(lvl * 5 + d) * 3) * 64 + lane;
        const bf16x8 W0 = wl[0];          // dy = -1
        const bf16x8 W1 = wl[64];         // dy =  0
        const bf16x8 W2 = wl[128];        // dy = +1

        bf16x8 G[6];
#pragma unroll
        for (int y = 0; y < 6; ++y)
            G[y] = *reinterpret_cast<const bf16x8*>(gp + y * 288);

        // OPERAND SWAP: A = weights (M=co), B = G (N=z) -> D[co][z]
        __builtin_amdgcn_s_setprio(1);
#pragma unroll
        for (int i = 0; i < 4; ++i)
            acc[i] = __builtin_amdgcn_mfma_f32_16x16x32_bf16(W0, G[i],     acc[i], 0, 0, 0);
#pragma unroll
        for (int i = 0; i < 4; ++i)
            acc[i] = __builtin_amdgcn_mfma_f32_16x16x32_bf16(W1, G[i + 1], acc[i], 0, 0, 0);
#pragma unroll
        for (int i = 0; i < 4; ++i)
            acc[i] = __builtin_amdgcn_mfma_f32_16x16x32_bf16(W2, G[i + 2], acc[i], 0, 0, 0);
        __builtin_amdgcn_s_setprio(0);
    }

    // ---- store (+bias), NONTEMPORAL dwordx4: lane = (z = lane&15,
    // channels 4*(lane>>4)..+3). Wave store = contiguous 1KB (full lines). ----
    const int cob = (lane >> 4) * 4;
    const f32x4 bv4 = *reinterpret_cast<const f32x4*>(&bias[lvl * 16 + cob]);
    const int gx = x0 + tx;
    const int zr = z0 + m;
    if ((gx < r) & (zr < r)) {
#pragma unroll
        for (int i = 0; i < 4; ++i) {
            const int gy = y0 + i;
            if (gy >= r) continue;
            float* p = out + ((size_t)base + ((size_t)gx * r + gy) * r + zr) * 16 + cob;
            const f32x4 v = acc[i] + bv4;
            __builtin_nontemporal_store(v, reinterpret_cast<f32x4*>(p));
        }
    }
}

// ---------------- fp32 fallback (round-0 verified, used only if ws tiny) -----
#define TPB 256
#define VPT 2
#define VPB (TPB * VPT)
#define NBLOCKS_F32 4207

__global__ __launch_bounds__(TPB) void conv3d_mr_kernel(
    const float* __restrict__ in, const float* __restrict__ wgt,
    const float* __restrict__ bias, float* __restrict__ out)
{
    constexpr int RES[16]  = {16, 18, 20, 23, 26, 29, 32, 36, 40, 45, 50, 56, 63, 70, 76, 80};
    constexpr int OFF[16]  = {0, 4096, 9928, 17928, 30095, 47671, 72060, 104828,
                              151484, 215484, 306609, 431609, 607225, 857272, 1200272, 1639248};
    constexpr int BOFF[16] = {0, 8, 20, 36, 60, 95, 143, 207, 299, 424, 602, 847, 1190, 1679, 2349, 3207};

    __shared__ __align__(16) float w_lds[27 * 256];

    const int b = blockIdx.x;
    int r = RES[0], base = OFF[0], bstart = BOFF[0], lvl = 0;
#pragma unroll
    for (int i = 1; i < 16; ++i)
        if (b >= BOFF[i]) { lvl = i; r = RES[i]; base = OFF[i]; bstart = BOFF[i]; }
    const int t3 = r * r * r;
    const int vstart = (b - bstart) * VPB;

    {
        const float4* ws = reinterpret_cast<const float4*>(wgt + lvl * 27 * 256);
        float4* wd = reinterpret_cast<float4*>(w_lds);
        for (int i = threadIdx.x; i < 27 * 64; i += TPB) wd[i] = ws[i];
    }
    __syncthreads();

    float bv[16];
    {
        const float4* bp = reinterpret_cast<const float4*>(bias + lvl * 16);
#pragma unroll
        for (int j = 0; j < 4; ++j) {
            float4 t = bp[j];
            bv[4*j+0] = t.x; bv[4*j+1] = t.y; bv[4*j+2] = t.z; bv[4*j+3] = t.w;
        }
    }

    int vx[VPT], vy[VPT], vz[VPT];
    bool live[VPT];
    float acc[VPT][16];
#pragma unroll
    for (int i = 0; i < VPT; ++i) {
        int v = vstart + (int)threadIdx.x + i * TPB;
        live[i] = (v < t3);
        if (!live[i]) v = 0;
        const int q = v / r;
        vz[i] = v - q * r; vx[i] = q / r; vy[i] = q - vx[i] * r;
#pragma unroll
        for (int co = 0; co < 16; ++co) acc[i][co] = bv[co];
    }

#pragma unroll 1
    for (int k = 0; k < 27; ++k) {
        const int dx = k / 9 - 1, dy = (k / 3) % 3 - 1, dz = k - (k / 3) * 3 - 1;
        float g[VPT][16];
#pragma unroll
        for (int i = 0; i < VPT; ++i) {
            const int nx = vx[i] + dx, ny = vy[i] + dy, nz = vz[i] + dz;
            const bool ok = live[i] && ((unsigned)nx < (unsigned)r) &&
                            ((unsigned)ny < (unsigned)r) && ((unsigned)nz < (unsigned)r);
            float4 a0 = make_float4(0.f,0.f,0.f,0.f), a1 = a0, a2 = a0, a3 = a0;
            if (ok) {
                const float4* p = reinterpret_cast<const float4*>(
                    in + (size_t)(base + (nx * r + ny) * r + nz) * 16);
                a0 = p[0]; a1 = p[1]; a2 = p[2]; a3 = p[3];
            }
            g[i][0]=a0.x; g[i][1]=a0.y; g[i][2]=a0.z; g[i][3]=a0.w;
            g[i][4]=a1.x; g[i][5]=a1.y; g[i][6]=a1.z; g[i][7]=a1.w;
            g[i][8]=a2.x; g[i][9]=a2.y; g[i][10]=a2.z; g[i][11]=a2.w;
            g[i][12]=a3.x; g[i][13]=a3.y; g[i][14]=a3.z; g[i][15]=a3.w;
        }
        const float4* wk = reinterpret_cast<const float4*>(&w_lds[k * 256]);
#pragma unroll
        for (int ci = 0; ci < 16; ++ci) {
            const float4 w0 = wk[ci*4+0], w1 = wk[ci*4+1], w2 = wk[ci*4+2], w3 = wk[ci*4+3];
#pragma unroll
            for (int i = 0; i < VPT; ++i) {
                const float gv = g[i][ci];
                acc[i][0]=fmaf(gv,w0.x,acc[i][0]);   acc[i][1]=fmaf(gv,w0.y,acc[i][1]);
                acc[i][2]=fmaf(gv,w0.z,acc[i][2]);   acc[i][3]=fmaf(gv,w0.w,acc[i][3]);
                acc[i][4]=fmaf(gv,w1.x,acc[i][4]);   acc[i][5]=fmaf(gv,w1.y,acc[i][5]);
                acc[i][6]=fmaf(gv,w1.z,acc[i][6]);   acc[i][7]=fmaf(gv,w1.w,acc[i][7]);
                acc[i][8]=fmaf(gv,w2.x,acc[i][8]);   acc[i][9]=fmaf(gv,w2.y,acc[i][9]);
                acc[i][10]=fmaf(gv,w2.z,acc[i][10]); acc[i][11]=fmaf(gv,w2.w,acc[i][11]);
                acc[i][12]=fmaf(gv,w3.x,acc[i][12]); acc[i][13]=fmaf(gv,w3.y,acc[i][13]);
                acc[i][14]=fmaf(gv,w3.z,acc[i][14]); acc[i][15]=fmaf(gv,w3.w,acc[i][15]);
            }
        }
    }

#pragma unroll
    for (int i = 0; i < VPT; ++i) {
        if (!live[i]) continue;
        const int v = vstart + (int)threadIdx.x + i * TPB;
        float4* po = reinterpret_cast<float4*>(out + (size_t)(base + v) * 16);
        po[0] = make_float4(acc[i][0],  acc[i][1],  acc[i][2],  acc[i][3]);
        po[1] = make_float4(acc[i][4],  acc[i][5],  acc[i][6],  acc[i][7]);
        po[2] = make_float4(acc[i][8],  acc[i][9],  acc[i][10], acc[i][11]);
        po[3] = make_float4(acc[i][12], acc[i][13], acc[i][14], acc[i][15]);
    }
}

extern "C" void kernel_launch(void* const* d_in, const int* in_sizes, int n_in,
                              void* d_out, int out_size, void* d_ws, size_t ws_size,
                              hipStream_t stream) {
    const float* in   = (const float*)d_in[0];
    const float* wgt  = (const float*)d_in[3];
    const float* bias = (const float*)d_in[4];
    float* out = (float*)d_out;

    constexpr size_t WF2_BYTES = 16 * 5 * 3 * 64 * 16;   // 245,760
    if (ws_size < WF2_BYTES) {
        conv3d_mr_kernel<<<NBLOCKS_F32, TPB, 0, stream>>>(in, wgt, bias, out);
        return;
    }

    uint4* wf2 = (uint4*)d_ws;
    wfrag2_kernel<<<16 * 5 * 3, 64, 0, stream>>>(wgt, wf2);
    conv_mfma_tile_kernel<<<NTILEBLKS, CTPB, 0, stream>>>(
        in, (const ushort*)wf2, bias, out);
}

// Round 17
// 61.330 us; speedup vs baseline: 1.0570x; 1.0236x over previous
//
#include <hip/hip_runtime.h>
#include <hip/hip_bf16.h>

// Multi-resolution dense 3x3x3 conv, CIN=COUT=16, bf16 MFMA, 3D LDS tiling.
// R16: R13 pipeline (operand-swap MFMA, full-line nt stores) on a 4x8x16
// tile with 512 THREADS (8 waves = 4 tx x 2 yhalf): R9 proved the bigger
// tile's per-voxel ratios (halo amp 2.11 vs 2.53, setup tax halved) but lost
// on occupancy (36%, 4-wave blocks LDS-capped). 512-thr blocks hit the wave
// cap instead: 4 blocks x 8 waves = 32 waves/CU. VGPR<=64 required ((512,8))
// — current code is 36, fits. Staging 5 predicated iters (was 6).
// Per wave: 5 duos x (6 ds_read_b128 + 12 MFMA), same as R7/R13.

typedef short bf16x8 __attribute__((ext_vector_type(8)));
typedef float f32x4  __attribute__((ext_vector_type(4)));

__device__ __forceinline__ unsigned f2bf(float f) {
    unsigned u = __float_as_uint(f);
    return (u + 0x7FFFu + ((u >> 16) & 1u)) >> 16;   // RNE
}
__device__ __forceinline__ unsigned pk2(float lo, float hi) {
    __hip_bfloat162 t = __float22bfloat162_rn(float2{lo, hi});
    return *reinterpret_cast<unsigned*>(&t);
}

__device__ __constant__ int c_DX0[5] = {-1,-1, 0, 1, 1};
__device__ __constant__ int c_DZ0[5] = {-1, 1, 0,-1, 1};
__device__ __constant__ int c_DX1[5] = {-1, 0, 0, 1, 1};
__device__ __constant__ int c_DZ1[5] = { 0,-1, 1, 0, 1};

// ---------------- pass 1: weight fragments in duo order ----------------
// wf2[lvl][duo][dyi][lane]: 8 bf16, elem j -> w[lvl][s][ci][co],
// s from (dx,dz) duo member (lane>>5) and dy=dyi; ci = ((lane>>4)&1)*8 + j,
// co = lane&15. Serves as MFMA A operand: A[m=co][k], k-block = lane>>4,
// identical k-mapping to the G fragment. duo4/ksel1 -> 0.
__global__ __launch_bounds__(64) void wfrag2_kernel(const float* __restrict__ wgt,
                                                    uint4* __restrict__ wf2) {
    const int b = blockIdx.x;                  // lvl*15 + duo*3 + dyi
    const int lvl = b / 15, rem = b % 15, duo = rem / 3, dyi = rem % 3;
    const int l = threadIdx.x;
    const int ksel = l >> 5;
    const int cib = ((l >> 4) & 1) * 8;
    const int co = l & 15;
    const bool zerow = (duo == 4) && (ksel == 1);
    const int dx = ksel ? c_DX1[duo] : c_DX0[duo];
    const int dz = ksel ? c_DZ1[duo] : c_DZ0[duo];
    const int s = (dx + 1) * 9 + dyi * 3 + (dz + 1);
    unsigned v[8];
#pragma unroll
    for (int j = 0; j < 8; ++j) {
        float f = zerow ? 0.f : wgt[(((lvl * 27 + s) * 16) + (cib + j)) * 16 + co];
        v[j] = f2bf(f);
    }
    uint4 pk;
    pk.x = v[0] | (v[1] << 16);
    pk.y = v[2] | (v[3] << 16);
    pk.z = v[4] | (v[5] << 16);
    pk.w = v[6] | (v[7] << 16);
    wf2[((lvl * 5 + duo) * 3 + dyi) * 64 + l] = pk;
}

// ---------------- pass 2: tiled MFMA conv (4x8x16 tile, 512 thr) ----------------
#define CTPB 512
#define NTILEBLKS 4817
#define PLANE 17344          // 1080 halo voxels * 16B + 64B bank-phase pad

__global__ __launch_bounds__(CTPB, 8) void conv_mfma_tile_kernel(
    const float* __restrict__ in, const ushort* __restrict__ wf2,
    const float* __restrict__ bias, float* __restrict__ out)
{
    constexpr int RES[16]   = {16, 18, 20, 23, 26, 29, 32, 36, 40, 45, 50, 56, 63, 70, 76, 80};
    constexpr int OFF[16]   = {0, 4096, 9928, 17928, 30095, 47671, 72060, 104828,
                               151484, 215484, 306609, 431609, 607225, 857272, 1200272, 1639248};
    // tiles per level = ceil(r/4)*ceil(r/8)*ceil(r/16); prefix:
    constexpr int TBOFF[16] = {0, 8, 38, 68, 104, 160, 224, 288, 423, 573,
                               789, 1153, 1545, 2057, 2867, 3817};
    // per-duo LDS byte shifts: (dx*180 + dz)*16 for members 0/1
    constexpr int SH0[5] = {-2896, -2864, 0, 2864, 2896};
    constexpr int SH1[5] = {-2880, -16, 16, 2880, 2896};

    __shared__ __align__(16) char lds[2 * PLANE];   // 34.7 KB

    // Bijective XCD swizzle (nwg=4817, q=602, rem=1).
    const int orig = blockIdx.x;
    const int xcd = orig & 7, idx = orig >> 3;
    const int b = (xcd < 1 ? xcd * 603 : 603 + (xcd - 1) * 602) + idx;

    int lvl = 0;
#pragma unroll
    for (int i = 1; i < 16; ++i) if (b >= TBOFF[i]) lvl = i;
    const int r    = RES[lvl];
    const int base = OFF[lvl];

    const int NTZ = (r + 15) >> 4;
    const int NTY = (r + 7) >> 3;
    int tid = b - TBOFF[lvl];
    const int nyz = NTY * NTZ;
    const int txi = tid / nyz;  tid -= txi * nyz;
    const int tyi = tid / NTZ;
    const int tzi = tid - tyi * NTZ;
    const int x0 = txi * 4, y0 = tyi * 8, z0 = tzi * 16;

    const int lane = threadIdx.x & 63;
    const int wave = threadIdx.x >> 6;

    // ---- stage, phase A: 10 unconditional clamped loads (branch-free) ----
    // j = tid + k*512 indexes 2160 16B-chunks (1080 halo voxels x 2 ci-halves).
    float4 raw[10];
    int    lofs[5];
    bool   val[5];
#pragma unroll
    for (int k = 0; k < 5; ++k) {
        const int j = (int)threadIdx.x + k * 512;
        const int half = j & 1;
        int h = j >> 1;
        if (k == 4) h = h > 1079 ? 1079 : h;     // overrun threads: clamp slot
        const int hx = h / 180;
        const int rem = h - hx * 180;
        const int hy = rem / 18;
        const int hz = rem - hy * 18;
        const int gx = x0 - 1 + hx, gy = y0 - 1 + hy, gz = z0 - 1 + hz;
        const bool v = ((unsigned)gx < (unsigned)r) & ((unsigned)gy < (unsigned)r) &
                       ((unsigned)gz < (unsigned)r);
        const int cx = gx < 0 ? 0 : (gx >= r ? r - 1 : gx);
        const int cy = gy < 0 ? 0 : (gy >= r ? r - 1 : gy);
        const int cz = gz < 0 ? 0 : (gz >= r ? r - 1 : gz);
        const float4* s = reinterpret_cast<const float4*>(
            in + ((size_t)base + ((size_t)cx * r + cy) * r + cz) * 16 + half * 8);
        raw[2 * k]     = s[0];
        raw[2 * k + 1] = s[1];
        val[k]  = v;
        lofs[k] = half * PLANE + h * 16;
    }
    __builtin_amdgcn_sched_barrier(0);   // keep loads batched above this point

    // ---- stage, phase B: cvt (unconditional) + mask + ds_write ----
#pragma unroll
    for (int k = 0; k < 5; ++k) {
        const float4 a = raw[2 * k], c2 = raw[2 * k + 1];
        uint4 pkv;
        pkv.x = pk2(a.x,  a.y);
        pkv.y = pk2(a.z,  a.w);
        pkv.z = pk2(c2.x, c2.y);
        pkv.w = pk2(c2.z, c2.w);
        if (!val[k]) pkv = uint4{0u, 0u, 0u, 0u};
        if (k < 4 || (int)threadIdx.x < 112)     // j < 2160
            *reinterpret_cast<uint4*>(lds + lofs[k]) = pkv;
    }
    __syncthreads();

    // ---- compute: wave = (tx, yhalf); 4 y-cols, 5 duos x (6 reads + 12 MFMA) ----
    const int m      = lane & 15;         // z within tile (B-operand N index)
    const int cihalf = (lane >> 4) & 1;
    const int ksel   = lane >> 5;
    const int tx     = wave & 3;
    const int yh     = wave >> 2;

    // lane base at duo-shift 0, halo row y' = yh*4: voxel (tx+1, yh*4, 1+m)
    const int base0 = cihalf * PLANE + ((tx + 1) * 180 + yh * 4 * 18 + 1 + m) * 16;

    f32x4 acc[4];
#pragma unroll
    for (int i = 0; i < 4; ++i) acc[i] = f32x4{0.f, 0.f, 0.f, 0.f};

#pragma unroll
    for (int d = 0; d < 5; ++d) {
        const int shift = ksel ? SH1[d] : SH0[d];
        const char* gp = lds + (base0 + shift);

        const bf16x8* wl = (const bf16x8*)wf2 + ((size_t)(lvl * 5 + d) * 3) * 64 + lane;
        const bf16x8 W0 = wl[0];          // dy = -1
        const bf16x8 W1 = wl[64];         // dy =  0
        const bf16x8 W2 = wl[128];        // dy = +1

        bf16x8 G[6];
#pragma unroll
        for (int y = 0; y < 6; ++y)
            G[y] = *reinterpret_cast<const bf16x8*>(gp + y * 288);

        // OPERAND SWAP: A = weights (M=co), B = G (N=z) -> D[co][z]
        __builtin_amdgcn_s_setprio(1);
#pragma unroll
        for (int i = 0; i < 4; ++i)
            acc[i] = __builtin_amdgcn_mfma_f32_16x16x32_bf16(W0, G[i],     acc[i], 0, 0, 0);
#pragma unroll
        for (int i = 0; i < 4; ++i)
            acc[i] = __builtin_amdgcn_mfma_f32_16x16x32_bf16(W1, G[i + 1], acc[i], 0, 0, 0);
#pragma unroll
        for (int i = 0; i < 4; ++i)
            acc[i] = __builtin_amdgcn_mfma_f32_16x16x32_bf16(W2, G[i + 2], acc[i], 0, 0, 0);
        __builtin_amdgcn_s_setprio(0);
    }

    // ---- store (+bias), NONTEMPORAL dwordx4: lane = (z = lane&15,
    // channels 4*(lane>>4)..+3). Wave store = contiguous 1KB (full lines). ----
    const int cob = (lane >> 4) * 4;
    const f32x4 bv4 = *reinterpret_cast<const f32x4*>(&bias[lvl * 16 + cob]);
    const int gx = x0 + tx;
    const int zr = z0 + m;
    if ((gx < r) & (zr < r)) {
#pragma unroll
        for (int i = 0; i < 4; ++i) {
            const int gy = y0 + yh * 4 + i;
            if (gy >= r) continue;
            float* p = out + ((size_t)base + ((size_t)gx * r + gy) * r + zr) * 16 + cob;
            const f32x4 v = acc[i] + bv4;
            __builtin_nontemporal_store(v, reinterpret_cast<f32x4*>(p));
        }
    }
}

// ---------------- fp32 fallback (round-0 verified, used only if ws tiny) -----
#define TPB 256
#define VPT 2
#define VPB (TPB * VPT)
#define NBLOCKS_F32 4207

__global__ __launch_bounds__(TPB) void conv3d_mr_kernel(
    const float* __restrict__ in, const float* __restrict__ wgt,
    const float* __restrict__ bias, float* __restrict__ out)
{
    constexpr int RES[16]  = {16, 18, 20, 23, 26, 29, 32, 36, 40, 45, 50, 56, 63, 70, 76, 80};
    constexpr int OFF[16]  = {0, 4096, 9928, 17928, 30095, 47671, 72060, 104828,
                              151484, 215484, 306609, 431609, 607225, 857272, 1200272, 1639248};
    constexpr int BOFF[16] = {0, 8, 20, 36, 60, 95, 143, 207, 299, 424, 602, 847, 1190, 1679, 2349, 3207};

    __shared__ __align__(16) float w_lds[27 * 256];

    const int b = blockIdx.x;
    int r = RES[0], base = OFF[0], bstart = BOFF[0], lvl = 0;
#pragma unroll
    for (int i = 1; i < 16; ++i)
        if (b >= BOFF[i]) { lvl = i; r = RES[i]; base = OFF[i]; bstart = BOFF[i]; }
    const int t3 = r * r * r;
    const int vstart = (b - bstart) * VPB;

    {
        const float4* ws = reinterpret_cast<const float4*>(wgt + lvl * 27 * 256);
        float4* wd = reinterpret_cast<float4*>(w_lds);
        for (int i = threadIdx.x; i < 27 * 64; i += TPB) wd[i] = ws[i];
    }
    __syncthreads();

    float bv[16];
    {
        const float4* bp = reinterpret_cast<const float4*>(bias + lvl * 16);
#pragma unroll
        for (int j = 0; j < 4; ++j) {
            float4 t = bp[j];
            bv[4*j+0] = t.x; bv[4*j+1] = t.y; bv[4*j+2] = t.z; bv[4*j+3] = t.w;
        }
    }

    int vx[VPT], vy[VPT], vz[VPT];
    bool live[VPT];
    float acc[VPT][16];
#pragma unroll
    for (int i = 0; i < VPT; ++i) {
        int v = vstart + (int)threadIdx.x + i * TPB;
        live[i] = (v < t3);
        if (!live[i]) v = 0;
        const int q = v / r;
        vz[i] = v - q * r; vx[i] = q / r; vy[i] = q - vx[i] * r;
#pragma unroll
        for (int co = 0; co < 16; ++co) acc[i][co] = bv[co];
    }

#pragma unroll 1
    for (int k = 0; k < 27; ++k) {
        const int dx = k / 9 - 1, dy = (k / 3) % 3 - 1, dz = k - (k / 3) * 3 - 1;
        float g[VPT][16];
#pragma unroll
        for (int i = 0; i < VPT; ++i) {
            const int nx = vx[i] + dx, ny = vy[i] + dy, nz = vz[i] + dz;
            const bool ok = live[i] && ((unsigned)nx < (unsigned)r) &&
                            ((unsigned)ny < (unsigned)r) && ((unsigned)nz < (unsigned)r);
            float4 a0 = make_float4(0.f,0.f,0.f,0.f), a1 = a0, a2 = a0, a3 = a0;
            if (ok) {
                const float4* p = reinterpret_cast<const float4*>(
                    in + (size_t)(base + (nx * r + ny) * r + nz) * 16);
                a0 = p[0]; a1 = p[1]; a2 = p[2]; a3 = p[3];
            }
            g[i][0]=a0.x; g[i][1]=a0.y; g[i][2]=a0.z; g[i][3]=a0.w;
            g[i][4]=a1.x; g[i][5]=a1.y; g[i][6]=a1.z; g[i][7]=a1.w;
            g[i][8]=a2.x; g[i][9]=a2.y; g[i][10]=a2.z; g[i][11]=a2.w;
            g[i][12]=a3.x; g[i][13]=a3.y; g[i][14]=a3.z; g[i][15]=a3.w;
        }
        const float4* wk = reinterpret_cast<const float4*>(&w_lds[k * 256]);
#pragma unroll
        for (int ci = 0; ci < 16; ++ci) {
            const float4 w0 = wk[ci*4+0], w1 = wk[ci*4+1], w2 = wk[ci*4+2], w3 = wk[ci*4+3];
#pragma unroll
            for (int i = 0; i < VPT; ++i) {
                const float gv = g[i][ci];
                acc[i][0]=fmaf(gv,w0.x,acc[i][0]);   acc[i][1]=fmaf(gv,w0.y,acc[i][1]);
                acc[i][2]=fmaf(gv,w0.z,acc[i][2]);   acc[i][3]=fmaf(gv,w0.w,acc[i][3]);
                acc[i][4]=fmaf(gv,w1.x,acc[i][4]);   acc[i][5]=fmaf(gv,w1.y,acc[i][5]);
                acc[i][6]=fmaf(gv,w1.z,acc[i][6]);   acc[i][7]=fmaf(gv,w1.w,acc[i][7]);
                acc[i][8]=fmaf(gv,w2.x,acc[i][8]);   acc[i][9]=fmaf(gv,w2.y,acc[i][9]);
                acc[i][10]=fmaf(gv,w2.z,acc[i][10]); acc[i][11]=fmaf(gv,w2.w,acc[i][11]);
                acc[i][12]=fmaf(gv,w3.x,acc[i][12]); acc[i][13]=fmaf(gv,w3.y,acc[i][13]);
                acc[i][14]=fmaf(gv,w3.z,acc[i][14]); acc[i][15]=fmaf(gv,w3.w,acc[i][15]);
            }
        }
    }

#pragma unroll
    for (int i = 0; i < VPT; ++i) {
        if (!live[i]) continue;
        const int v = vstart + (int)threadIdx.x + i * TPB;
        float4* po = reinterpret_cast<float4*>(out + (size_t)(base + v) * 16);
        po[0] = make_float4(acc[i][0],  acc[i][1],  acc[i][2],  acc[i][3]);
        po[1] = make_float4(acc[i][4],  acc[i][5],  acc[i][6],  acc[i][7]);
        po[2] = make_float4(acc[i][8],  acc[i][9],  acc[i][10], acc[i][11]);
        po[3] = make_float4(acc[i][12], acc[i][13], acc[i][14], acc[i][15]);
    }
}

extern "C" void kernel_launch(void* const* d_in, const int* in_sizes, int n_in,
                              void* d_out, int out_size, void* d_ws, size_t ws_size,
                              hipStream_t stream) {
    const float* in   = (const float*)d_in[0];
    const float* wgt  = (const float*)d_in[3];
    const float* bias = (const float*)d_in[4];
    float* out = (float*)d_out;

    constexpr size_t WF2_BYTES = 16 * 5 * 3 * 64 * 16;   // 245,760
    if (ws_size < WF2_BYTES) {
        conv3d_mr_kernel<<<NBLOCKS_F32, TPB, 0, stream>>>(in, wgt, bias, out);
        return;
    }

    uint4* wf2 = (uint4*)d_ws;
    wfrag2_kernel<<<16 * 5 * 3, 64, 0, stream>>>(wgt, wf2);
    conv_mfma_tile_kernel<<<NTILEBLKS, CTPB, 0, stream>>>(
        in, (const ushort*)wf2, bias, out);
}